// Round 2
// baseline (211.318 us; speedup 1.0000x reference)
//
#include <hip/hip_runtime.h>
#include <math.h>

#define S_LEN 2048
#define NB    2
#define CQ_   256
#define CC_   256
#define DH    50
#define KW    101
#define PS    100
#define RB    16

// ---------------------------------------------------------------------------
// Kernel 0: transpose W_p [PS][CC] -> WpT [CC][PS] so k_align reads coalesced.
// ---------------------------------------------------------------------------
__global__ __launch_bounds__(256) void k_wpT(const float* __restrict__ Wp,
                                             float* __restrict__ WpT) {
  const int j = blockIdx.x;    // 0..PS-1
  const int c = threadIdx.x;   // 0..CC-1
  WpT[c * PS + j] = Wp[j * CC_ + c];
}

// ---------------------------------------------------------------------------
// Kernel 1: per block of RB rows: V[r][:] = c[r] @ W_a  (v = W_a^T c), and
// p[r] = S * sigmoid( sum_j V_p[j] * tanh( sum_c c[r][c] * W_p[j][c] ) ).
// V is written into d_out (same size as the final output); k_attn consumes
// its own row and overwrites it. C-tile values are wave-uniform -> s_load;
// W_a / WpT column reads are coalesced across tid.
// ---------------------------------------------------------------------------
__global__ __launch_bounds__(256) void k_align(const float* __restrict__ ct,
    const float* __restrict__ Wa, const float* __restrict__ WpT,
    const float* __restrict__ Vp, float* __restrict__ p_out,
    float* __restrict__ V_out) {
  const int r0  = blockIdx.x * RB;
  const int tid = threadIdx.x;
  float accV[RB], accH[RB];
#pragma unroll
  for (int r = 0; r < RB; ++r) { accV[r] = 0.0f; accH[r] = 0.0f; }

  const float* crow = ct + (size_t)r0 * CC_;
  const bool hasH = (tid < PS);

  for (int c = 0; c < CC_; ++c) {
    const float wa = Wa[c * CQ_ + tid];
    const float wp = hasH ? WpT[c * PS + tid] : 0.0f;
#pragma unroll
    for (int r = 0; r < RB; ++r) {
      const float cv = crow[r * CC_ + c];   // uniform -> s_load
      accV[r] = fmaf(cv, wa, accV[r]);
      accH[r] = fmaf(cv, wp, accH[r]);
    }
  }

#pragma unroll
  for (int r = 0; r < RB; ++r)
    V_out[(size_t)(r0 + r) * CQ_ + tid] = accV[r];

  __shared__ float red[RB][132];            // +4 pad: breaks bank aliasing
  if (hasH) {
    const float vp = Vp[tid];
#pragma unroll
    for (int r = 0; r < RB; ++r) red[r][tid] = vp * tanhf(accH[r]);
  }
  __syncthreads();
  if (tid < RB) {
    float s = 0.0f;
    for (int j = 0; j < PS; ++j) s += red[tid][j];
    const float sig = 1.0f / (1.0f + expf(-s));
    p_out[r0 + tid] = (float)S_LEN * sig;
  }
}

// ---------------------------------------------------------------------------
// Kernel 2: one block (256 thr = 4 waves) per (b,s) row.
//   V aliases out (same buffer): block `row` reads only V[row] and writes
//   only out[row], with __syncthreads (vmcnt-draining) between -> safe.
//   idx semantics match ref exactly: raw = trunc((p + offs) + 1); valid iff
//   1 <= raw <= S (clip to [0,S+1] then %(S+1) maps 0 and S+1 to invalid 0).
// ---------------------------------------------------------------------------
__global__ __launch_bounds__(256) void k_attn(const float* __restrict__ q,
    const float* __restrict__ p_in, const float* V,   // no restrict: aliases out
    float* out) {
  const int row  = blockIdx.x;            // 0..NB*S-1
  const int b    = row >> 11;             // row / S_LEN
  const int tid  = threadIdx.x;
  const int lane = tid & 63;
  const int wave = tid >> 6;

  __shared__ int   sidx[KW];              // safe gather row (clamped), 0-based
  __shared__ int   svalid[KW];            // 1 if window slot valid
  __shared__ float sa[128];
  __shared__ float rbuf[128];
  __shared__ float sw[KW];

  const float p  = p_in[row];
  const float tp = truncf(p);

  if (tid < 128) sa[tid] = -INFINITY;
  if (tid < KW) {
    const float t = p + (float)(tid - DH) + 1.0f;   // (p + offs) + 1, ref order
    const int raw = (int)truncf(t);                 // trunc toward zero
    const int ok  = (raw >= 1 && raw <= S_LEN) ? 1 : 0;
    svalid[tid] = ok;
    sidx[tid]   = ok ? (raw - 1) : 0;               // clamped safe row
  }
  __syncthreads();

  const float* vrow = V + (size_t)row * CQ_;
  const float vv0 = vrow[lane];
  const float vv1 = vrow[64 + lane];
  const float vv2 = vrow[128 + lane];
  const float vv3 = vrow[192 + lane];
  const float* qb = q + (size_t)b * S_LEN * CQ_;

  for (int k = wave; k < KW; k += 4) {
    if (svalid[k]) {                        // LDS broadcast -> wave-uniform
      const float* qr = qb + (size_t)sidx[k] * CQ_;
      float part = qr[lane] * vv0;
      part = fmaf(qr[64  + lane], vv1, part);
      part = fmaf(qr[128 + lane], vv2, part);
      part = fmaf(qr[192 + lane], vv3, part);
#pragma unroll
      for (int off = 32; off > 0; off >>= 1)
        part += __shfl_down(part, off, 64);
      if (lane == 0) sa[k] = part;
    }
  }
  __syncthreads();

  // max over sa[0..127] (-inf padded)
  if (tid < 128) rbuf[tid] = sa[tid];
  __syncthreads();
  for (int s2 = 64; s2 > 0; s2 >>= 1) {
    if (tid < s2) rbuf[tid] = fmaxf(rbuf[tid], rbuf[tid + s2]);
    __syncthreads();
  }
  const float mx = rbuf[0];
  __syncthreads();
  if (tid < 128) rbuf[tid] = expf(sa[tid] - mx);   // masked: exp(-inf)=0
  __syncthreads();
  for (int s2 = 64; s2 > 0; s2 >>= 1) {
    if (tid < s2) rbuf[tid] += rbuf[tid + s2];
    __syncthreads();
  }
  const float denom = rbuf[0];
  __syncthreads();

  if (tid < KW) {
    float g = ((float)(tid - DH) + tp - p) / (float)DH;  // ref op order + true div
    g = -2.0f * g * g;
    // masked slots: sa=-inf -> weight exactly 0 -> branch-free output pass
    sw[tid] = expf(sa[tid] - mx) * expf(g) / denom;
  }
  __syncthreads();

  float acc = 0.0f;
  for (int k = 0; k < KW; ++k)            // branch-free: zero-weight masked
    acc = fmaf(sw[k], qb[(size_t)sidx[k] * CQ_ + tid], acc);
  out[(size_t)row * CQ_ + tid] = acc;
}

// ---------------------------------------------------------------------------
extern "C" void kernel_launch(void* const* d_in, const int* in_sizes, int n_in,
                              void* d_out, int out_size, void* d_ws, size_t ws_size,
                              hipStream_t stream) {
  const float* q  = (const float*)d_in[0];
  const float* ct = (const float*)d_in[1];
  const float* Wa = (const float*)d_in[2];
  const float* Wp = (const float*)d_in[3];
  const float* Vp = (const float*)d_in[4];
  float* out = (float*)d_out;

  // ws layout (floats): p[NB*S] | WpT[CC*PS]  -> 116 KB total.
  // V (4 MB) lives in d_out: k_align writes it, k_attn row-locally replaces it.
  float* ws     = (float*)d_ws;
  float* p_ws   = ws;
  float* WpT_ws = ws + NB * S_LEN;

  k_wpT  <<<PS, 256, 0, stream>>>(Wp, WpT_ws);
  k_align<<<(NB * S_LEN) / RB, 256, 0, stream>>>(ct, Wa, WpT_ws, Vp, p_ws, out);
  k_attn <<<NB * S_LEN, 256, 0, stream>>>(q, p_ws, out, out);
}

// Round 3
// 158.543 us; speedup vs baseline: 1.3329x; 1.3329x over previous
//
#include <hip/hip_runtime.h>
#include <math.h>

#define S_LEN 2048
#define NB    2
#define CQ_   256
#define CC_   256
#define DH    50
#define KW    101
#define PS    100
#define RB    8

// ---------------------------------------------------------------------------
// Kernel 0: transpose W_p [PS][CC] -> WpT [CC][PS] so k_align reads coalesced.
// ---------------------------------------------------------------------------
__global__ __launch_bounds__(256) void k_wpT(const float* __restrict__ Wp,
                                             float* __restrict__ WpT) {
  const int j = blockIdx.x;    // 0..PS-1
  const int c = threadIdx.x;   // 0..CC-1
  WpT[c * PS + j] = Wp[j * CC_ + c];
}

// ---------------------------------------------------------------------------
// Kernel 1: per block of RB=8 rows: V[r][:] = c[r] @ W_a  (v = W_a^T c) and
// p[r] = S * sigmoid( sum_j V_p[j] * tanh( sum_c c[r][c] * W_p[j][c] ) ).
// ct tile staged in LDS (float4), c-loop unrolled x4: per step 4 coalesced
// Wa loads (+4 WpT for tid<100), 8 ds_read_b128 broadcasts, 64 FMAs.
// Grid 512 -> 2 blocks/CU. V written into d_out (k_attn is row-local on it).
// ---------------------------------------------------------------------------
__global__ __launch_bounds__(256) void k_align(const float* __restrict__ ct,
    const float* __restrict__ Wa, const float* __restrict__ WpT,
    const float* __restrict__ Vp, float* __restrict__ p_out,
    float* __restrict__ V_out) {
  const int r0  = blockIdx.x * RB;
  const int tid = threadIdx.x;

  __shared__ float sc[RB][CC_];                  // 8 KB ct tile
  {
    const float4* src = (const float4*)(ct + (size_t)r0 * CC_);
    float4* dst = (float4*)&sc[0][0];
    dst[tid]       = src[tid];
    dst[tid + 256] = src[tid + 256];
  }
  __syncthreads();

  float accV[RB], accH[RB];
#pragma unroll
  for (int r = 0; r < RB; ++r) { accV[r] = 0.0f; accH[r] = 0.0f; }
  const bool hasH = (tid < PS);

  for (int c = 0; c < CC_; c += 4) {
    const float wa0 = Wa[(c + 0) * CQ_ + tid];
    const float wa1 = Wa[(c + 1) * CQ_ + tid];
    const float wa2 = Wa[(c + 2) * CQ_ + tid];
    const float wa3 = Wa[(c + 3) * CQ_ + tid];
    float wp0 = 0.0f, wp1 = 0.0f, wp2 = 0.0f, wp3 = 0.0f;
    if (hasH) {
      wp0 = WpT[(c + 0) * PS + tid];
      wp1 = WpT[(c + 1) * PS + tid];
      wp2 = WpT[(c + 2) * PS + tid];
      wp3 = WpT[(c + 3) * PS + tid];
    }
#pragma unroll
    for (int r = 0; r < RB; ++r) {
      const float4 cv = *(const float4*)&sc[r][c];
      accV[r] = fmaf(cv.x, wa0, accV[r]);
      accV[r] = fmaf(cv.y, wa1, accV[r]);
      accV[r] = fmaf(cv.z, wa2, accV[r]);
      accV[r] = fmaf(cv.w, wa3, accV[r]);
      accH[r] = fmaf(cv.x, wp0, accH[r]);
      accH[r] = fmaf(cv.y, wp1, accH[r]);
      accH[r] = fmaf(cv.z, wp2, accH[r]);
      accH[r] = fmaf(cv.w, wp3, accH[r]);
    }
  }

#pragma unroll
  for (int r = 0; r < RB; ++r)
    V_out[(size_t)(r0 + r) * CQ_ + tid] = accV[r];

  __shared__ float red[RB][PS + 4];
  if (hasH) {
    const float vp = Vp[tid];
#pragma unroll
    for (int r = 0; r < RB; ++r) red[r][tid] = vp * tanhf(accH[r]);
  }
  __syncthreads();
  if (tid < RB) {
    float s = 0.0f;
    for (int j = 0; j < PS; ++j) s += red[tid][j];
    const float sig = 1.0f / (1.0f + expf(-s));
    p_out[r0 + tid] = (float)S_LEN * sig;
  }
}

// ---------------------------------------------------------------------------
// Kernel 2: ONE ROW PER WAVE, online softmax, single gather pass, no barriers.
//   raw = trunc((p + offs) + 1); valid iff 1 <= raw <= S (== ref clip/mod).
//   raw is wave-uniform (p is per-row) -> coherent branches.
//   Numerator folds the gaussian: out = (sum gauss_k e^{s_k-m} q_k) / (sum e^{s_k-m}).
//   V aliases out: wave reads only V[row] (into regs) then writes out[row].
// ---------------------------------------------------------------------------
__global__ __launch_bounds__(256) void k_attn(const float* __restrict__ q,
    const float* __restrict__ p_in, const float* V,   // no restrict: aliases out
    float* out) {
  const int row  = (blockIdx.x << 2) + (threadIdx.x >> 6);
  const int lane = threadIdx.x & 63;
  const int b    = row >> 11;

  const float p  = p_in[row];
  const float tp = truncf(p);
  const float4 vv = *(const float4*)(V + (size_t)row * CQ_ + lane * 4);
  const float* qb = q + (size_t)b * S_LEN * CQ_;

  float m = -INFINITY, l = 0.0f;
  float4 acc = make_float4(0.0f, 0.0f, 0.0f, 0.0f);

  for (int k = 0; k < KW; ++k) {
    const float t = p + (float)(k - DH) + 1.0f;   // ref op order
    const int raw = (int)t;                       // trunc toward zero
    if (raw < 1 || raw > S_LEN) continue;         // wave-uniform
    const float4 qv = *(const float4*)(qb + (size_t)(raw - 1) * CQ_ + lane * 4);

    float s = qv.x * vv.x;
    s = fmaf(qv.y, vv.y, s);
    s = fmaf(qv.z, vv.z, s);
    s = fmaf(qv.w, vv.w, s);
#pragma unroll
    for (int off = 1; off < 64; off <<= 1)
      s += __shfl_xor(s, off, 64);                // all lanes -> full dot

    float g = (float)(k - DH) + tp - p;
    g = g / (float)DH;                            // true divide, ref order
    const float gauss = __expf(-2.0f * (g * g));

    if (s > m) {                                  // uniform: s identical on all lanes
      const float alpha = __expf(m - s);          // first hit: exp(-inf)=0
      l = fmaf(l, alpha, 1.0f);
      acc.x = fmaf(acc.x, alpha, gauss * qv.x);
      acc.y = fmaf(acc.y, alpha, gauss * qv.y);
      acc.z = fmaf(acc.z, alpha, gauss * qv.z);
      acc.w = fmaf(acc.w, alpha, gauss * qv.w);
      m = s;
    } else {
      const float w = __expf(s - m);
      l += w;
      const float wg = w * gauss;
      acc.x = fmaf(wg, qv.x, acc.x);
      acc.y = fmaf(wg, qv.y, acc.y);
      acc.z = fmaf(wg, qv.z, acc.z);
      acc.w = fmaf(wg, qv.w, acc.w);
    }
  }

  const float inv = 1.0f / l;
  float4 o;
  o.x = acc.x * inv; o.y = acc.y * inv; o.z = acc.z * inv; o.w = acc.w * inv;
  *(float4*)(out + (size_t)row * CQ_ + lane * 4) = o;
}

// ---------------------------------------------------------------------------
extern "C" void kernel_launch(void* const* d_in, const int* in_sizes, int n_in,
                              void* d_out, int out_size, void* d_ws, size_t ws_size,
                              hipStream_t stream) {
  const float* q  = (const float*)d_in[0];
  const float* ct = (const float*)d_in[1];
  const float* Wa = (const float*)d_in[2];
  const float* Wp = (const float*)d_in[3];
  const float* Vp = (const float*)d_in[4];
  float* out = (float*)d_out;

  // ws layout (floats): p[NB*S] | WpT[CC*PS]  -> 118 KB total.
  float* ws     = (float*)d_ws;
  float* p_ws   = ws;
  float* WpT_ws = ws + NB * S_LEN;

  k_wpT  <<<PS, 256, 0, stream>>>(Wp, WpT_ws);
  k_align<<<(NB * S_LEN) / RB, 256, 0, stream>>>(ct, Wa, WpT_ws, Vp, p_ws, out);
  k_attn <<<(NB * S_LEN) / 4, 256, 0, stream>>>(q, p_ws, out, out);
}

// Round 4
// 136.777 us; speedup vs baseline: 1.5450x; 1.1591x over previous
//
#include <hip/hip_runtime.h>
#include <math.h>

#define S_LEN 2048
#define NB    2
#define CQ_   256
#define CC_   256
#define DH    50
#define KW    101
#define PS    100
#define RB    8
#define HPAD  128   // zero-padded hidden width (branch-free loads)

// ---------------------------------------------------------------------------
// k_prep: WpT[c][j] = (j<100) ? Wp[j][c] : 0.   WpT: [256][128] in ws.
// ---------------------------------------------------------------------------
__global__ __launch_bounds__(128) void k_prep(const float* __restrict__ Wp,
                                              float* __restrict__ WpT) {
  const int c = blockIdx.x, j = threadIdx.x;
  WpT[c * HPAD + j] = (j < PS) ? Wp[j * CC_ + c] : 0.0f;
}

// ---------------------------------------------------------------------------
// k_align: 384 threads / block, RB=8 rows. tid<256: V column tid (stream Wa);
// tid>=256: hidden unit tid-256 (stream padded WpT). Branch-free inner loop,
// software-pipelined loads (prefetch distance 8 rows), ct tile in LDS.
// p-path reduction kept BIT-IDENTICAL to the R2/R3 passing version
// (trunc(p) boundaries are discontinuous in the final gather).
// ---------------------------------------------------------------------------
__global__ __launch_bounds__(384) void k_align(const float* __restrict__ ct,
    const float* __restrict__ Wa, const float* __restrict__ WpT,
    const float* __restrict__ Vp, float* __restrict__ p_out,
    float* __restrict__ V_out) {
  const int r0  = blockIdx.x * RB;
  const int tid = threadIdx.x;

  __shared__ float sc[RB][CC_];                 // 8 KB ct tile
  {
    const float4* src = (const float4*)(ct + (size_t)r0 * CC_);
    float4* dst = (float4*)&sc[0][0];
    for (int i = tid; i < RB * CC_ / 4; i += 384) dst[i] = src[i];
  }
  __syncthreads();

  const float* wbase;
  int w1s;
  if (tid < CQ_) { wbase = Wa + tid;          w1s = CQ_;  }
  else           { wbase = WpT + (tid - CQ_); w1s = HPAD; }
  const int w2s = 2 * w1s, w3s = 3 * w1s, w4s = 4 * w1s;

  float acc[RB];
#pragma unroll
  for (int r = 0; r < RB; ++r) acc[r] = 0.0f;

  // pipeline: A = rows c..c+3, B = rows c+4..c+7, prefetch rows c+8..c+11
  float a0 = wbase[0], a1 = wbase[w1s], a2 = wbase[w2s], a3 = wbase[w3s];
  const float* wpB = wbase + w4s;
  float b0 = wpB[0], b1 = wpB[w1s], b2 = wpB[w2s], b3 = wpB[w3s];
  const float* wpN = wbase + 2 * w4s;

  for (int c = 0; c < CC_; c += 4) {
    const float* wpn = (c + 8 < CC_) ? wpN : wbase;   // tail prefetch unused
    const float n0 = wpn[0], n1 = wpn[w1s], n2 = wpn[w2s], n3 = wpn[w3s];
#pragma unroll
    for (int r = 0; r < RB; ++r) {
      const float4 cv = *(const float4*)&sc[r][c];
      float t = acc[r];                 // order x,y,z,w == R2/R3 (p bit-exact)
      t = fmaf(cv.x, a0, t);
      t = fmaf(cv.y, a1, t);
      t = fmaf(cv.z, a2, t);
      t = fmaf(cv.w, a3, t);
      acc[r] = t;
    }
    a0 = b0; a1 = b1; a2 = b2; a3 = b3;
    b0 = n0; b1 = n1; b2 = n2; b3 = n3;
    wpN += w4s;
  }

  if (tid < CQ_) {
#pragma unroll
    for (int r = 0; r < RB; ++r)
      V_out[(size_t)(r0 + r) * CQ_ + tid] = acc[r];
  }

  __shared__ float red[RB][PS + 4];
  if (tid >= CQ_) {
    const int j = tid - CQ_;
    if (j < PS) {
      const float vp = Vp[j];
#pragma unroll
      for (int r = 0; r < RB; ++r) red[r][j] = vp * tanhf(acc[r]);
    }
  }
  __syncthreads();
  if (tid < RB) {                       // serial j-sum: identical to R2/R3
    float s = 0.0f;
    for (int j = 0; j < PS; ++j) s += red[tid][j];
    p_out[r0 + tid] = (float)S_LEN * (1.0f / (1.0f + expf(-s)));
  }
}

// ---------------------------------------------------------------------------
// k_attn: one row per wave, TWO-PHASE (chain-free).
//  A: 101 independent score steps (branch-free clamp, unroll-8 ILP);
//     lane l captures scores k=l and k=64+l in registers.
//  B: one wave-level max/sum reduction; weights (softmax*gauss/den) to LDS.
//  C: weighted gather, skipping weights < 1e-5 (peaked softmax => ~90% skip;
//     dropped-mass error <= 101*1e-5*|q|max ~ 5e-3, margin is 6.7e-2).
//  Zero __syncthreads. V aliases out (row-local, read-then-write).
// ---------------------------------------------------------------------------
__global__ __launch_bounds__(256) void k_attn(const float* __restrict__ q,
    const float* __restrict__ p_in, const float* V,   // aliases out
    float* out) {
  const int wid  = threadIdx.x >> 6;
  const int row  = (blockIdx.x << 2) + wid;
  const int lane = threadIdx.x & 63;
  const int b    = row >> 11;

  __shared__ float sw[4][KW + 3];

  const float p  = p_in[row];
  const float tp = truncf(p);
  const float4 vv = *(const float4*)(V + (size_t)row * CQ_ + lane * 4);
  const float* qb = q + (size_t)b * S_LEN * CQ_;

  float s0 = -INFINITY, s1 = -INFINITY;

#pragma unroll 8
  for (int k = 0; k < 64; ++k) {
    const float t  = p + (float)(k - DH) + 1.0f;    // ref op order
    const int raw  = (int)t;                        // trunc toward zero
    const bool ok  = (raw >= 1 && raw <= S_LEN);
    const int r    = ok ? raw - 1 : 0;
    const float4 qv = *(const float4*)(qb + (size_t)r * CQ_ + lane * 4);
    float s = qv.x * vv.x;
    s = fmaf(qv.y, vv.y, s);
    s = fmaf(qv.z, vv.z, s);
    s = fmaf(qv.w, vv.w, s);
#pragma unroll
    for (int off = 1; off < 64; off <<= 1) s += __shfl_xor(s, off, 64);
    s = ok ? s : -INFINITY;
    if (lane == k) s0 = s;
  }
#pragma unroll 4
  for (int k = 64; k < KW; ++k) {
    const float t  = p + (float)(k - DH) + 1.0f;
    const int raw  = (int)t;
    const bool ok  = (raw >= 1 && raw <= S_LEN);
    const int r    = ok ? raw - 1 : 0;
    const float4 qv = *(const float4*)(qb + (size_t)r * CQ_ + lane * 4);
    float s = qv.x * vv.x;
    s = fmaf(qv.y, vv.y, s);
    s = fmaf(qv.z, vv.z, s);
    s = fmaf(qv.w, vv.w, s);
#pragma unroll
    for (int off = 1; off < 64; off <<= 1) s += __shfl_xor(s, off, 64);
    s = ok ? s : -INFINITY;
    if (lane == k - 64) s1 = s;
  }

  float m = fmaxf(s0, s1);
#pragma unroll
  for (int off = 1; off < 64; off <<= 1) m = fmaxf(m, __shfl_xor(m, off, 64));

  const float e0 = __expf(s0 - m);                  // -inf -> 0
  const float e1 = __expf(s1 - m);
  float den = e0 + e1;
#pragma unroll
  for (int off = 1; off < 64; off <<= 1) den += __shfl_xor(den, off, 64);
  const float inv = 1.0f / den;

  float g0 = ((float)(lane - DH) + tp - p) / (float)DH;       // k = lane
  float g1 = ((float)(lane + (64 - DH)) + tp - p) / (float)DH; // k = 64+lane
  const float w0 = e0 * __expf(-2.0f * g0 * g0) * inv;
  const float w1 = e1 * __expf(-2.0f * g1 * g1) * inv;
  sw[wid][lane] = w0;
  if (lane < KW - 64) sw[wid][64 + lane] = w1;
  // wave-private LDS region: no barrier needed (compiler orders via lgkmcnt)

  float4 acc = make_float4(0.0f, 0.0f, 0.0f, 0.0f);
  for (int k = 0; k < KW; ++k) {
    const float wk = sw[wid][k];                    // broadcast, wave-uniform
    if (wk > 1e-5f) {                               // uniform skip branch
      const float t = p + (float)(k - DH) + 1.0f;
      const int r   = (int)t - 1;                   // wk>0 implies valid
      const float4 qv = *(const float4*)(qb + (size_t)r * CQ_ + lane * 4);
      acc.x = fmaf(wk, qv.x, acc.x);
      acc.y = fmaf(wk, qv.y, acc.y);
      acc.z = fmaf(wk, qv.z, acc.z);
      acc.w = fmaf(wk, qv.w, acc.w);
    }
  }
  *(float4*)(out + (size_t)row * CQ_ + lane * 4) = acc;
}

// ---------------------------------------------------------------------------
extern "C" void kernel_launch(void* const* d_in, const int* in_sizes, int n_in,
                              void* d_out, int out_size, void* d_ws, size_t ws_size,
                              hipStream_t stream) {
  const float* q  = (const float*)d_in[0];
  const float* ct = (const float*)d_in[1];
  const float* Wa = (const float*)d_in[2];
  const float* Wp = (const float*)d_in[3];
  const float* Vp = (const float*)d_in[4];
  float* out = (float*)d_out;

  // ws (floats): p[4096] | WpT[256*128]  -> 147 KB
  float* ws     = (float*)d_ws;
  float* p_ws   = ws;
  float* WpT_ws = ws + NB * S_LEN;

  k_prep <<<CC_, HPAD, 0, stream>>>(Wp, WpT_ws);
  k_align<<<(NB * S_LEN) / RB, 384, 0, stream>>>(ct, Wa, WpT_ws, Vp, p_ws, out);
  k_attn <<<(NB * S_LEN) / 4, 256, 0, stream>>>(q, p_ws, out, out);
}

// Round 5
// 128.138 us; speedup vs baseline: 1.6491x; 1.0674x over previous
//
#include <hip/hip_runtime.h>
#include <math.h>

#define S_LEN 2048
#define NB    2
#define CQ_   256
#define CC_   256
#define DH    50
#define KW    101
#define PS    100
#define RB    4     // rows per k_align block: 1024 blocks -> 4/CU -> 75% occ
#define HPAD  128   // zero-padded hidden width (branch-free loads)

// ---------------------------------------------------------------------------
// k_prep: WpT[c][j] = (j<100) ? Wp[j][c] : 0.   WpT: [256][128] in ws.
// ---------------------------------------------------------------------------
__global__ __launch_bounds__(128) void k_prep(const float* __restrict__ Wp,
                                              float* __restrict__ WpT) {
  const int c = blockIdx.x, j = threadIdx.x;
  WpT[c * HPAD + j] = (j < PS) ? Wp[j * CC_ + c] : 0.0f;
}

// ---------------------------------------------------------------------------
// k_align: 384 thr, RB=4 rows/block (grid 1024 -> 24 waves/CU; R4 was
// grid-capped at 12). tid<256: V column tid (stream Wa); tid>=256: hidden
// unit tid-256 (stream padded WpT). p-path fmaf sequence BIT-IDENTICAL to
// the passing R2..R4 versions (trunc(p) boundaries are discontinuous).
// ---------------------------------------------------------------------------
__global__ __launch_bounds__(384) void k_align(const float* __restrict__ ct,
    const float* __restrict__ Wa, const float* __restrict__ WpT,
    const float* __restrict__ Vp, float* __restrict__ p_out,
    float* __restrict__ V_out) {
  const int r0  = blockIdx.x * RB;
  const int tid = threadIdx.x;

  __shared__ float sc[RB][CC_];                 // 4 KB ct tile
  {
    const float4* src = (const float4*)(ct + (size_t)r0 * CC_);
    float4* dst = (float4*)&sc[0][0];
    if (tid < RB * CC_ / 4) dst[tid] = src[tid];
  }
  __syncthreads();

  const float* wp;
  int w1s;
  if (tid < CQ_) { wp = Wa + tid;          w1s = CQ_;  }
  else           { wp = WpT + (tid - CQ_); w1s = HPAD; }
  const int w2s = 2 * w1s, w3s = 3 * w1s, w4s = 4 * w1s;

  float acc[RB];
#pragma unroll
  for (int r = 0; r < RB; ++r) acc[r] = 0.0f;

#pragma unroll 2
  for (int c = 0; c < CC_; c += 4) {
    const float w0 = wp[0];
    const float w1 = wp[w1s];
    const float w2 = wp[w2s];
    const float w3 = wp[w3s];
#pragma unroll
    for (int r = 0; r < RB; ++r) {
      const float4 cv = *(const float4*)&sc[r][c];
      float t = acc[r];                 // fmaf order x,y,z,w == R2..R4
      t = fmaf(cv.x, w0, t);
      t = fmaf(cv.y, w1, t);
      t = fmaf(cv.z, w2, t);
      t = fmaf(cv.w, w3, t);
      acc[r] = t;
    }
    wp += w4s;
  }

  if (tid < CQ_) {
#pragma unroll
    for (int r = 0; r < RB; ++r)
      V_out[(size_t)(r0 + r) * CQ_ + tid] = acc[r];
  }

  __shared__ float red[RB][PS + 4];
  if (tid >= CQ_ && tid < CQ_ + PS) {
    const int j = tid - CQ_;
    const float vp = Vp[j];
#pragma unroll
    for (int r = 0; r < RB; ++r) red[r][j] = vp * tanhf(acc[r]);
  }
  __syncthreads();
  if (tid < RB) {                       // serial j-sum: identical to R2..R4
    float s = 0.0f;
    for (int j = 0; j < PS; ++j) s += red[tid][j];
    p_out[r0 + tid] = (float)S_LEN * (1.0f / (1.0f + expf(-s)));
  }
}

// ---------------------------------------------------------------------------
// k_attn: one row per wave. Phase A: 26 group-steps, each computing FOUR
// scores at once — sub=lane>>4 picks window slot k=4g+sub, lane&15 picks a
// 16-float column stripe (4x float4 loads + 16 FMA), reduced with only 4
// __shfl_xor (1,2,4,8: stays inside the 16-lane subgroup). 4 independent
// rows in flight per step (x2 unroll = 8) for MLP; DS ops ~130 vs R4's 606.
// Phase B: one wave softmax from LDS scores. Phase C: weighted gather with
// uniform weight-skip. Zero __syncthreads. V aliases out (row-local).
// ---------------------------------------------------------------------------
__global__ __launch_bounds__(256) void k_attn(const float* __restrict__ q,
    const float* __restrict__ p_in, const float* V,   // aliases out
    float* out) {
  const int wid  = threadIdx.x >> 6;
  const int row  = (blockIdx.x << 2) + wid;
  const int lane = threadIdx.x & 63;
  const int b    = row >> 11;

  __shared__ float ss[4][128];   // scores (101 used, 101..127 = -inf)
  __shared__ float sw[4][128];   // final weights

  const float p  = p_in[row];
  const float tp = truncf(p);
  const float* qb = q + (size_t)b * S_LEN * CQ_;

  const int sub = lane >> 4;          // window-slot within group
  const int cb  = (lane & 15) * 16;   // column stripe base

  const float* vrow = V + (size_t)row * CQ_ + cb;
  const float4 v0 = *(const float4*)(vrow);
  const float4 v1 = *(const float4*)(vrow + 4);
  const float4 v2 = *(const float4*)(vrow + 8);
  const float4 v3 = *(const float4*)(vrow + 12);

  if (lane >= KW - 64) ss[wid][64 + lane] = -INFINITY;   // slots 101..127

#pragma unroll 2
  for (int g = 0; g < 26; ++g) {
    const int k = (g << 2) + sub;                  // uniform per 16-subgroup
    const float t = p + (float)(k - DH) + 1.0f;    // ref op order
    const int raw = (int)t;                        // trunc toward zero
    const bool ok = (raw >= 1) && (raw <= S_LEN) && (k < KW);
    const int r = ok ? raw - 1 : 0;
    const float* qr = qb + (size_t)r * CQ_ + cb;
    const float4 q0 = *(const float4*)(qr);
    const float4 q1 = *(const float4*)(qr + 4);
    const float4 q2 = *(const float4*)(qr + 8);
    const float4 q3 = *(const float4*)(qr + 12);

    float s = q0.x * v0.x;
    s = fmaf(q0.y, v0.y, s);
    s = fmaf(q0.z, v0.z, s);
    s = fmaf(q0.w, v0.w, s);
    s = fmaf(q1.x, v1.x, s);
    s = fmaf(q1.y, v1.y, s);
    s = fmaf(q1.z, v1.z, s);
    s = fmaf(q1.w, v1.w, s);
    s = fmaf(q2.x, v2.x, s);
    s = fmaf(q2.y, v2.y, s);
    s = fmaf(q2.z, v2.z, s);
    s = fmaf(q2.w, v2.w, s);
    s = fmaf(q3.x, v3.x, s);
    s = fmaf(q3.y, v3.y, s);
    s = fmaf(q3.z, v3.z, s);
    s = fmaf(q3.w, v3.w, s);

    s += __shfl_xor(s, 1, 64);    // reduce inside the 16-lane subgroup
    s += __shfl_xor(s, 2, 64);
    s += __shfl_xor(s, 4, 64);
    s += __shfl_xor(s, 8, 64);
    s = ok ? s : -INFINITY;
    if ((lane & 15) == 0) ss[wid][k] = s;
  }

  const float s0 = ss[wid][lane];
  const float s1 = ss[wid][64 + lane];

  float m = fmaxf(s0, s1);
#pragma unroll
  for (int off = 1; off < 64; off <<= 1) m = fmaxf(m, __shfl_xor(m, off, 64));

  const float e0 = __expf(s0 - m);                  // -inf -> 0
  const float e1 = __expf(s1 - m);
  float den = e0 + e1;
#pragma unroll
  for (int off = 1; off < 64; off <<= 1) den += __shfl_xor(den, off, 64);
  const float inv = 1.0f / den;

  float g0 = ((float)(lane - DH) + tp - p) / (float)DH;        // k = lane
  float g1 = ((float)(lane + (64 - DH)) + tp - p) / (float)DH; // k = 64+lane
  const float w0 = e0 * __expf(-2.0f * g0 * g0) * inv;
  const float w1 = e1 * __expf(-2.0f * g1 * g1) * inv;
  sw[wid][lane] = w0;
  if (lane < KW - 64) sw[wid][64 + lane] = w1;
  // wave-private LDS region: intra-wave lgkmcnt ordering suffices

  float4 acc = make_float4(0.0f, 0.0f, 0.0f, 0.0f);
  for (int k = 0; k < KW; ++k) {
    const float wk = sw[wid][k];                    // broadcast, wave-uniform
    if (wk > 1e-5f) {                               // uniform skip branch
      const float t = p + (float)(k - DH) + 1.0f;
      const int r   = (int)t - 1;                   // wk>0 implies valid
      const float4 qv = *(const float4*)(qb + (size_t)r * CQ_ + lane * 4);
      acc.x = fmaf(wk, qv.x, acc.x);
      acc.y = fmaf(wk, qv.y, acc.y);
      acc.z = fmaf(wk, qv.z, acc.z);
      acc.w = fmaf(wk, qv.w, acc.w);
    }
  }
  *(float4*)(out + (size_t)row * CQ_ + lane * 4) = acc;
}

// ---------------------------------------------------------------------------
extern "C" void kernel_launch(void* const* d_in, const int* in_sizes, int n_in,
                              void* d_out, int out_size, void* d_ws, size_t ws_size,
                              hipStream_t stream) {
  const float* q  = (const float*)d_in[0];
  const float* ct = (const float*)d_in[1];
  const float* Wa = (const float*)d_in[2];
  const float* Wp = (const float*)d_in[3];
  const float* Vp = (const float*)d_in[4];
  float* out = (float*)d_out;

  // ws (floats): p[4096] | WpT[256*128]  -> 147 KB
  float* ws     = (float*)d_ws;
  float* p_ws   = ws;
  float* WpT_ws = ws + NB * S_LEN;

  k_prep <<<CC_, HPAD, 0, stream>>>(Wp, WpT_ws);
  k_align<<<(NB * S_LEN) / RB, 384, 0, stream>>>(ct, Wa, WpT_ws, Vp, p_ws, out);
  k_attn <<<(NB * S_LEN) / 4, 256, 0, stream>>>(q, p_ws, out, out);
}

// Round 6
// 121.713 us; speedup vs baseline: 1.7362x; 1.0528x over previous
//
#include <hip/hip_runtime.h>
#include <math.h>

#define S_LEN 2048
#define NB    2
#define CQ_   256
#define CC_   256
#define DH    50
#define KW    101
#define PS    100
#define RB    8     // rows per k_align block
#define HPAD  128   // zero-padded hidden width (branch-free loads)
#define WTH   1e-5f // phase-C weight skip threshold

// ---------------------------------------------------------------------------
// k_prep: WpT[c][j] = (j<100) ? Wp[j][c] : 0.   WpT: [256][128] in ws.
// ---------------------------------------------------------------------------
__global__ __launch_bounds__(128) void k_prep(const float* __restrict__ Wp,
                                              float* __restrict__ WpT) {
  const int c = blockIdx.x, j = threadIdx.x;
  WpT[c * HPAD + j] = (j < PS) ? Wp[j * CC_ + c] : 0.0f;
}

// ---------------------------------------------------------------------------
// k_align: 256 thr, RB=8 rows/block, NO LDS for ct. ct reads are wave-uniform
// float4 -> compiler emits s_load_dwordx4 (scalar pipe; R5 showed the LDS
// version is ds_read-throughput-bound at ~23us/CU). Waves 0-1: 2 V columns
// per thread (float2 Wa loads). Waves 2-3: hidden units (padded WpT).
// p-path fmaf sequence BIT-IDENTICAL to R2..R5 (trunc(p) discontinuities).
// ---------------------------------------------------------------------------
__global__ __launch_bounds__(256) void k_align(const float* __restrict__ ct,
    const float* __restrict__ Wa, const float* __restrict__ WpT,
    const float* __restrict__ Vp, float* __restrict__ p_out,
    float* __restrict__ V_out) {
  const int r0  = blockIdx.x * RB;
  const int tid = threadIdx.x;
  const float* crow = ct + (size_t)r0 * CC_;   // uniform base

  __shared__ float red[RB][PS + 4];

  if (tid < 128) {
    // ---- V path: columns 2*tid, 2*tid+1 ----
    const float* wa = Wa + 2 * tid;
    float a0[RB], a1[RB];
#pragma unroll
    for (int r = 0; r < RB; ++r) { a0[r] = 0.0f; a1[r] = 0.0f; }

#pragma unroll 2
    for (int c = 0; c < CC_; c += 4) {
      const float2 w0 = *(const float2*)(wa + (size_t)(c + 0) * CQ_);
      const float2 w1 = *(const float2*)(wa + (size_t)(c + 1) * CQ_);
      const float2 w2 = *(const float2*)(wa + (size_t)(c + 2) * CQ_);
      const float2 w3 = *(const float2*)(wa + (size_t)(c + 3) * CQ_);
#pragma unroll
      for (int r = 0; r < RB; ++r) {
        const float4 cv = *(const float4*)&crow[r * CC_ + c];  // uniform->s_load
        float t0 = a0[r], t1 = a1[r];
        t0 = fmaf(cv.x, w0.x, t0);  t1 = fmaf(cv.x, w0.y, t1);
        t0 = fmaf(cv.y, w1.x, t0);  t1 = fmaf(cv.y, w1.y, t1);
        t0 = fmaf(cv.z, w2.x, t0);  t1 = fmaf(cv.z, w2.y, t1);
        t0 = fmaf(cv.w, w3.x, t0);  t1 = fmaf(cv.w, w3.y, t1);
        a0[r] = t0; a1[r] = t1;
      }
    }
#pragma unroll
    for (int r = 0; r < RB; ++r) {
      float2 o; o.x = a0[r]; o.y = a1[r];
      *(float2*)(V_out + (size_t)(r0 + r) * CQ_ + 2 * tid) = o;
    }
  } else {
    // ---- hidden path: unit j = tid-128 (j<100 live, rest padded zeros) ----
    const int j = tid - 128;
    const float* wh = WpT + j;
    float ah[RB];
#pragma unroll
    for (int r = 0; r < RB; ++r) ah[r] = 0.0f;

#pragma unroll 2
    for (int c = 0; c < CC_; c += 4) {
      const float w0 = wh[(size_t)(c + 0) * HPAD];
      const float w1 = wh[(size_t)(c + 1) * HPAD];
      const float w2 = wh[(size_t)(c + 2) * HPAD];
      const float w3 = wh[(size_t)(c + 3) * HPAD];
#pragma unroll
      for (int r = 0; r < RB; ++r) {
        const float4 cv = *(const float4*)&crow[r * CC_ + c];  // uniform->s_load
        float t = ah[r];                  // fmaf order x,y,z,w == R2..R5
        t = fmaf(cv.x, w0, t);
        t = fmaf(cv.y, w1, t);
        t = fmaf(cv.z, w2, t);
        t = fmaf(cv.w, w3, t);
        ah[r] = t;
      }
    }
    if (j < PS) {
      const float vp = Vp[j];
#pragma unroll
      for (int r = 0; r < RB; ++r) red[r][j] = vp * tanhf(ah[r]);
    }
  }
  __syncthreads();
  if (tid < RB) {                         // serial j-sum: identical to R2..R5
    float s = 0.0f;
    for (int j = 0; j < PS; ++j) s += red[tid][j];
    p_out[r0 + tid] = (float)S_LEN * (1.0f / (1.0f + expf(-s)));
  }
}

// ---------------------------------------------------------------------------
// k_attn: one row per wave.
//  Phase A: 26 group-steps; sub=lane>>4 picks k=4g+sub, lane&15 picks a
//   16-float stripe. Dot as 4-way independent tree (short dep chain), 4
//   subgroup shfl_xor; unroll 4 for load overlap.
//  Phase B: wave softmax from LDS scores; gaussian folded into weights.
//  Phase C: ballot-compacted survivor walk (w>1e-5, ~10 rows): k via ctzll,
//   weight via __shfl from owner lane, scalar-based float4 gather. No LDS
//   polling. Dropped-mass error <= 101*1e-5*|q| ~ 5e-3 (margin 6.7e-2).
//  Zero __syncthreads. V aliases out (row-local read-then-write).
// ---------------------------------------------------------------------------
__global__ __launch_bounds__(256) void k_attn(const float* __restrict__ q,
    const float* __restrict__ p_in, const float* V,   // aliases out
    float* out) {
  const int wid  = threadIdx.x >> 6;
  const int row  = (blockIdx.x << 2) + wid;
  const int lane = threadIdx.x & 63;
  const int b    = row >> 11;

  __shared__ float ss[4][128];   // scores (101 used, 101..127 = -inf)

  const float p  = p_in[row];
  const float tp = truncf(p);
  const float* qb = q + (size_t)b * S_LEN * CQ_;

  const int sub = lane >> 4;          // window-slot within group
  const int cb  = (lane & 15) * 16;   // column stripe base

  const float* vrow = V + (size_t)row * CQ_ + cb;
  const float4 v0 = *(const float4*)(vrow);
  const float4 v1 = *(const float4*)(vrow + 4);
  const float4 v2 = *(const float4*)(vrow + 8);
  const float4 v3 = *(const float4*)(vrow + 12);

  if (lane >= KW - 64) ss[wid][64 + lane] = -INFINITY;   // slots 101..127

#pragma unroll 4
  for (int g = 0; g < 26; ++g) {
    const int k = (g << 2) + sub;                  // uniform per 16-subgroup
    const float t = p + (float)(k - DH) + 1.0f;    // ref op order
    const int raw = (int)t;                        // trunc toward zero
    const bool ok = (raw >= 1) && (raw <= S_LEN) && (k < KW);
    const int r = ok ? raw - 1 : 0;
    const float* qr = qb + (size_t)r * CQ_ + cb;
    const float4 q0 = *(const float4*)(qr);
    const float4 q1 = *(const float4*)(qr + 4);
    const float4 q2 = *(const float4*)(qr + 8);
    const float4 q3 = *(const float4*)(qr + 12);

    // 4 independent chains, then tree-combine (dep chain ~6 ops, not 16)
    float t0 = q0.x * v0.x;
    float t1 = q1.x * v1.x;
    float t2 = q2.x * v2.x;
    float t3 = q3.x * v3.x;
    t0 = fmaf(q0.y, v0.y, t0);
    t1 = fmaf(q1.y, v1.y, t1);
    t2 = fmaf(q2.y, v2.y, t2);
    t3 = fmaf(q3.y, v3.y, t3);
    t0 = fmaf(q0.z, v0.z, t0);
    t1 = fmaf(q1.z, v1.z, t1);
    t2 = fmaf(q2.z, v2.z, t2);
    t3 = fmaf(q3.z, v3.z, t3);
    t0 = fmaf(q0.w, v0.w, t0);
    t1 = fmaf(q1.w, v1.w, t1);
    t2 = fmaf(q2.w, v2.w, t2);
    t3 = fmaf(q3.w, v3.w, t3);
    float s = (t0 + t1) + (t2 + t3);

    s += __shfl_xor(s, 1, 64);    // reduce inside the 16-lane subgroup
    s += __shfl_xor(s, 2, 64);
    s += __shfl_xor(s, 4, 64);
    s += __shfl_xor(s, 8, 64);
    s = ok ? s : -INFINITY;
    if ((lane & 15) == 0) ss[wid][k] = s;
  }

  const float s0 = ss[wid][lane];
  const float s1 = ss[wid][64 + lane];

  float m = fmaxf(s0, s1);
#pragma unroll
  for (int off = 1; off < 64; off <<= 1) m = fmaxf(m, __shfl_xor(m, off, 64));

  const float e0 = __expf(s0 - m);                  // -inf -> 0
  const float e1 = __expf(s1 - m);
  float den = e0 + e1;
#pragma unroll
  for (int off = 1; off < 64; off <<= 1) den += __shfl_xor(den, off, 64);
  const float inv = 1.0f / den;

  float g0 = ((float)(lane - DH) + tp - p) / (float)DH;        // k = lane
  float g1 = ((float)(lane + (64 - DH)) + tp - p) / (float)DH; // k = 64+lane
  const float w0 = e0 * __expf(-2.0f * g0 * g0) * inv;
  const float w1 = e1 * __expf(-2.0f * g1 * g1) * inv;

  // ---- Phase C: ballot-compacted survivor walk ----
  unsigned long long m0 = __ballot(w0 > WTH);
  unsigned long long m1 = __ballot((lane < KW - 64) && (w1 > WTH));

  float4 acc = make_float4(0.0f, 0.0f, 0.0f, 0.0f);
  while (m0) {
    const int k = __builtin_ctzll(m0);
    m0 &= m0 - 1;
    const float wk = __shfl(w0, k, 64);
    const float t = p + (float)(k - DH) + 1.0f;     // ref op order
    const int r = (int)t - 1;                       // w>0 implies valid
    const float4 qv = *(const float4*)(qb + (size_t)r * CQ_ + lane * 4);
    acc.x = fmaf(wk, qv.x, acc.x);
    acc.y = fmaf(wk, qv.y, acc.y);
    acc.z = fmaf(wk, qv.z, acc.z);
    acc.w = fmaf(wk, qv.w, acc.w);
  }
  while (m1) {
    const int k = __builtin_ctzll(m1);
    m1 &= m1 - 1;
    const float wk = __shfl(w1, k, 64);
    const float t = p + (float)(k + (64 - DH)) + 1.0f;
    const int r = (int)t - 1;
    const float4 qv = *(const float4*)(qb + (size_t)r * CQ_ + lane * 4);
    acc.x = fmaf(wk, qv.x, acc.x);
    acc.y = fmaf(wk, qv.y, acc.y);
    acc.z = fmaf(wk, qv.z, acc.z);
    acc.w = fmaf(wk, qv.w, acc.w);
  }
  *(float4*)(out + (size_t)row * CQ_ + lane * 4) = acc;
}

// ---------------------------------------------------------------------------
extern "C" void kernel_launch(void* const* d_in, const int* in_sizes, int n_in,
                              void* d_out, int out_size, void* d_ws, size_t ws_size,
                              hipStream_t stream) {
  const float* q  = (const float*)d_in[0];
  const float* ct = (const float*)d_in[1];
  const float* Wa = (const float*)d_in[2];
  const float* Wp = (const float*)d_in[3];
  const float* Vp = (const float*)d_in[4];
  float* out = (float*)d_out;

  // ws (floats): p[4096] | WpT[256*128]  -> 147 KB
  float* ws     = (float*)d_ws;
  float* p_ws   = ws;
  float* WpT_ws = ws + NB * S_LEN;

  k_prep <<<CC_, HPAD, 0, stream>>>(Wp, WpT_ws);
  k_align<<<(NB * S_LEN) / RB, 256, 0, stream>>>(ct, Wa, WpT_ws, Vp, p_ws, out);
  k_attn <<<(NB * S_LEN) / 4, 256, 0, stream>>>(q, p_ws, out, out);
}

// Round 7
// 120.065 us; speedup vs baseline: 1.7600x; 1.0137x over previous
//
#include <hip/hip_runtime.h>
#include <math.h>

#define S_LEN 2048
#define NB    2
#define CQ_   256
#define CC_   256
#define DH    50
#define KW    101
#define PS    100
#define RB    8     // rows per k_align block
#define HPAD  128   // zero-padded hidden width (branch-free loads)
#define WTH   1e-5f // phase-C weight skip threshold

// ---------------------------------------------------------------------------
// k_prep: WpT[c][j] = (j<100) ? Wp[j][c] : 0.   WpT: [256][128] in ws.
// ---------------------------------------------------------------------------
__global__ __launch_bounds__(128) void k_prep(const float* __restrict__ Wp,
                                              float* __restrict__ WpT) {
  const int c = blockIdx.x, j = threadIdx.x;
  WpT[c * HPAD + j] = (j < PS) ? Wp[j * CC_ + c] : 0.0f;
}

// ---------------------------------------------------------------------------
// k_align: 384 thr (6 waves), RB=8 rows, grid 512 -> 12 waves/CU.
// tid<256: V column tid (Wa stream). tid>=256: hidden unit tid-256 (WpT).
// MANUAL 1-quad-ahead rotation: R6's VGPR=36 proved the compiler built no
// pipeline — every c-quad exposed a full s_load latency. cv0/cv1 are
// wave-uniform float4 (SGPR quads); w-next in named VGPRs.
// Hidden-path fmaf sequence BIT-IDENTICAL to R2..R6 (trunc(p) boundaries).
// ---------------------------------------------------------------------------
__global__ __launch_bounds__(384, 3) void k_align(const float* __restrict__ ct,
    const float* __restrict__ Wa, const float* __restrict__ WpT,
    const float* __restrict__ Vp, float* __restrict__ p_out,
    float* __restrict__ V_out) {
  const int r0  = blockIdx.x * RB;
  const int tid = threadIdx.x;
  const float* crow = ct + (size_t)r0 * CC_;   // uniform base

  __shared__ float red[RB][PS + 4];

  if (tid < CQ_) {
    // ---- V path: column tid, 8 rows ----
    const float* wa = Wa + tid;
    float acc[RB];
#pragma unroll
    for (int r = 0; r < RB; ++r) acc[r] = 0.0f;

    float4 cv0[RB], cv1[RB];
#pragma unroll
    for (int r = 0; r < RB; ++r) cv0[r] = *(const float4*)&crow[r * CC_];
    float w00 = wa[0 * CQ_], w01 = wa[1 * CQ_], w02 = wa[2 * CQ_], w03 = wa[3 * CQ_];

    for (int c = 0; c < CC_ - 4; c += 4) {
      const int cn = c + 4;
#pragma unroll
      for (int r = 0; r < RB; ++r) cv1[r] = *(const float4*)&crow[r * CC_ + cn];
      const float w10 = wa[(size_t)(cn + 0) * CQ_];
      const float w11 = wa[(size_t)(cn + 1) * CQ_];
      const float w12 = wa[(size_t)(cn + 2) * CQ_];
      const float w13 = wa[(size_t)(cn + 3) * CQ_];
#pragma unroll
      for (int r = 0; r < RB; ++r) {
        float t = acc[r];
        t = fmaf(cv0[r].x, w00, t);
        t = fmaf(cv0[r].y, w01, t);
        t = fmaf(cv0[r].z, w02, t);
        t = fmaf(cv0[r].w, w03, t);
        acc[r] = t;
      }
#pragma unroll
      for (int r = 0; r < RB; ++r) cv0[r] = cv1[r];
      w00 = w10; w01 = w11; w02 = w12; w03 = w13;
    }
#pragma unroll
    for (int r = 0; r < RB; ++r) {           // epilogue quad c=252
      float t = acc[r];
      t = fmaf(cv0[r].x, w00, t);
      t = fmaf(cv0[r].y, w01, t);
      t = fmaf(cv0[r].z, w02, t);
      t = fmaf(cv0[r].w, w03, t);
      acc[r] = t;
    }
#pragma unroll
    for (int r = 0; r < RB; ++r)
      V_out[(size_t)(r0 + r) * CQ_ + tid] = acc[r];
  } else {
    // ---- hidden path: unit j = tid-256 (j<100 live, rest padded zeros) ----
    const int j = tid - CQ_;
    const float* wh = WpT + j;
    float ah[RB];
#pragma unroll
    for (int r = 0; r < RB; ++r) ah[r] = 0.0f;

    float4 cv0[RB], cv1[RB];
#pragma unroll
    for (int r = 0; r < RB; ++r) cv0[r] = *(const float4*)&crow[r * CC_];
    float w00 = wh[0 * HPAD], w01 = wh[1 * HPAD], w02 = wh[2 * HPAD], w03 = wh[3 * HPAD];

    for (int c = 0; c < CC_ - 4; c += 4) {
      const int cn = c + 4;
#pragma unroll
      for (int r = 0; r < RB; ++r) cv1[r] = *(const float4*)&crow[r * CC_ + cn];
      const float w10 = wh[(size_t)(cn + 0) * HPAD];
      const float w11 = wh[(size_t)(cn + 1) * HPAD];
      const float w12 = wh[(size_t)(cn + 2) * HPAD];
      const float w13 = wh[(size_t)(cn + 3) * HPAD];
#pragma unroll
      for (int r = 0; r < RB; ++r) {
        float t = ah[r];                     // fmaf order x,y,z,w == R2..R6
        t = fmaf(cv0[r].x, w00, t);
        t = fmaf(cv0[r].y, w01, t);
        t = fmaf(cv0[r].z, w02, t);
        t = fmaf(cv0[r].w, w03, t);
        ah[r] = t;
      }
#pragma unroll
      for (int r = 0; r < RB; ++r) cv0[r] = cv1[r];
      w00 = w10; w01 = w11; w02 = w12; w03 = w13;
    }
#pragma unroll
    for (int r = 0; r < RB; ++r) {           // epilogue quad c=252
      float t = ah[r];
      t = fmaf(cv0[r].x, w00, t);
      t = fmaf(cv0[r].y, w01, t);
      t = fmaf(cv0[r].z, w02, t);
      t = fmaf(cv0[r].w, w03, t);
      ah[r] = t;
    }
    if (j < PS) {
      const float vp = Vp[j];
#pragma unroll
      for (int r = 0; r < RB; ++r) red[r][j] = vp * tanhf(ah[r]);
    }
  }
  __syncthreads();
  if (tid < RB) {                         // serial j-sum: identical to R2..R6
    float s = 0.0f;
    for (int j = 0; j < PS; ++j) s += red[tid][j];
    p_out[r0 + tid] = (float)S_LEN * (1.0f / (1.0f + expf(-s)));
  }
}

// ---------------------------------------------------------------------------
// k_attn: one row per wave.
//  Phase A: 13 paired steps (manual 2-step pipeline: 8 float4 loads in
//   flight); sub=lane>>4 picks k, lane&15 picks a 16-float stripe; dot as
//   4 independent chains + tree combine; 4 subgroup shfl_xor per score.
//  Phase B: wave softmax; weights (softmax*gauss/den) stored to LDS sw.
//  Phase C: batch-4 survivor walk — pop 4 set bits per outer iter (scalar
//   ctz), weights from LDS, 4 INDEPENDENT global loads in flight (R6's
//   while-loop serialized one L3 latency per survivor).
//  Zero __syncthreads. V aliases out (row-local read-then-write).
// ---------------------------------------------------------------------------
__global__ __launch_bounds__(256, 4) void k_attn(const float* __restrict__ q,
    const float* __restrict__ p_in, const float* V,   // aliases out
    float* out) {
  const int wid  = threadIdx.x >> 6;
  const int row  = (blockIdx.x << 2) + wid;
  const int lane = threadIdx.x & 63;
  const int b    = row >> 11;

  __shared__ float ss[4][128];   // scores (101..127 = -inf)
  __shared__ float sw[4][128];   // final weights

  const float p  = p_in[row];
  const float tp = truncf(p);
  const float* qb = q + (size_t)b * S_LEN * CQ_;

  const int sub = lane >> 4;          // window-slot within group
  const int cb  = (lane & 15) * 16;   // column stripe base

  const float* vrow = V + (size_t)row * CQ_ + cb;
  const float4 v0 = *(const float4*)(vrow);
  const float4 v1 = *(const float4*)(vrow + 4);
  const float4 v2 = *(const float4*)(vrow + 8);
  const float4 v3 = *(const float4*)(vrow + 12);

  if (lane >= KW - 64) ss[wid][64 + lane] = -INFINITY;   // slots 101..127

  for (int g = 0; g < 26; g += 2) {
    const int ka = (g << 2) + sub;                 // uniform per 16-subgroup
    const int kb = ka + 4;
    const float ta = p + (float)(ka - DH) + 1.0f;  // ref op order
    const float tb = p + (float)(kb - DH) + 1.0f;
    const int rawa = (int)ta;                      // trunc toward zero
    const int rawb = (int)tb;
    const bool oka = (rawa >= 1) && (rawa <= S_LEN) && (ka < KW);
    const bool okb = (rawb >= 1) && (rawb <= S_LEN) && (kb < KW);
    const float* qra = qb + (size_t)(oka ? rawa - 1 : 0) * CQ_ + cb;
    const float* qrb = qb + (size_t)(okb ? rawb - 1 : 0) * CQ_ + cb;

    // issue all 8 loads before either dot (manual 2-step pipeline)
    const float4 a0 = *(const float4*)(qra);
    const float4 a1 = *(const float4*)(qra + 4);
    const float4 a2 = *(const float4*)(qra + 8);
    const float4 a3 = *(const float4*)(qra + 12);
    const float4 b0 = *(const float4*)(qrb);
    const float4 b1 = *(const float4*)(qrb + 4);
    const float4 b2 = *(const float4*)(qrb + 8);
    const float4 b3 = *(const float4*)(qrb + 12);

    float t0 = a0.x * v0.x, t1 = a1.x * v1.x, t2 = a2.x * v2.x, t3 = a3.x * v3.x;
    t0 = fmaf(a0.y, v0.y, t0); t1 = fmaf(a1.y, v1.y, t1);
    t2 = fmaf(a2.y, v2.y, t2); t3 = fmaf(a3.y, v3.y, t3);
    t0 = fmaf(a0.z, v0.z, t0); t1 = fmaf(a1.z, v1.z, t1);
    t2 = fmaf(a2.z, v2.z, t2); t3 = fmaf(a3.z, v3.z, t3);
    t0 = fmaf(a0.w, v0.w, t0); t1 = fmaf(a1.w, v1.w, t1);
    t2 = fmaf(a2.w, v2.w, t2); t3 = fmaf(a3.w, v3.w, t3);
    float sA = (t0 + t1) + (t2 + t3);
    sA += __shfl_xor(sA, 1, 64);
    sA += __shfl_xor(sA, 2, 64);
    sA += __shfl_xor(sA, 4, 64);
    sA += __shfl_xor(sA, 8, 64);
    sA = oka ? sA : -INFINITY;
    if ((lane & 15) == 0) ss[wid][ka] = sA;

    float u0 = b0.x * v0.x, u1 = b1.x * v1.x, u2 = b2.x * v2.x, u3 = b3.x * v3.x;
    u0 = fmaf(b0.y, v0.y, u0); u1 = fmaf(b1.y, v1.y, u1);
    u2 = fmaf(b2.y, v2.y, u2); u3 = fmaf(b3.y, v3.y, u3);
    u0 = fmaf(b0.z, v0.z, u0); u1 = fmaf(b1.z, v1.z, u1);
    u2 = fmaf(b2.z, v2.z, u2); u3 = fmaf(b3.z, v3.z, u3);
    u0 = fmaf(b0.w, v0.w, u0); u1 = fmaf(b1.w, v1.w, u1);
    u2 = fmaf(b2.w, v2.w, u2); u3 = fmaf(b3.w, v3.w, u3);
    float sB = (u0 + u1) + (u2 + u3);
    sB += __shfl_xor(sB, 1, 64);
    sB += __shfl_xor(sB, 2, 64);
    sB += __shfl_xor(sB, 4, 64);
    sB += __shfl_xor(sB, 8, 64);
    sB = okb ? sB : -INFINITY;
    if ((lane & 15) == 0) ss[wid][kb] = sB;
  }

  const float s0 = ss[wid][lane];
  const float s1 = ss[wid][64 + lane];

  float m = fmaxf(s0, s1);
#pragma unroll
  for (int off = 1; off < 64; off <<= 1) m = fmaxf(m, __shfl_xor(m, off, 64));

  const float e0 = __expf(s0 - m);                  // -inf -> 0
  const float e1 = __expf(s1 - m);
  float den = e0 + e1;
#pragma unroll
  for (int off = 1; off < 64; off <<= 1) den += __shfl_xor(den, off, 64);
  const float inv = 1.0f / den;

  float g0 = ((float)(lane - DH) + tp - p) / (float)DH;        // k = lane
  float g1 = ((float)(lane + (64 - DH)) + tp - p) / (float)DH; // k = 64+lane
  const float w0 = e0 * __expf(-2.0f * g0 * g0) * inv;
  const float w1 = e1 * __expf(-2.0f * g1 * g1) * inv;
  sw[wid][lane] = w0;
  if (lane < KW - 64) sw[wid][64 + lane] = w1;
  // wave-private LDS rows: intra-wave lgkmcnt ordering suffices

  // ---- Phase C: batch-4 survivor walk (ascending k order preserved) ----
  unsigned long long m0 = __ballot(w0 > WTH);
  unsigned long long m1 = __ballot((lane < KW - 64) && (w1 > WTH));

  float4 acc = make_float4(0.0f, 0.0f, 0.0f, 0.0f);
  while ((m0 | m1) != 0ull) {
    int kk[4];
#pragma unroll
    for (int i = 0; i < 4; ++i) {
      int k = -1;
      if (m0)      { k = __builtin_ctzll(m0);      m0 &= m0 - 1; }
      else if (m1) { k = 64 + __builtin_ctzll(m1); m1 &= m1 - 1; }
      kk[i] = k;
    }
#pragma unroll
    for (int i = 0; i < 4; ++i) {
      if (kk[i] >= 0) {                             // wave-uniform
        const float wk = sw[wid][kk[i]];
        const float t = p + (float)(kk[i] - DH) + 1.0f;
        const int r = (int)t - 1;                   // w>0 implies valid
        const float4 qv = *(const float4*)(qb + (size_t)r * CQ_ + lane * 4);
        acc.x = fmaf(wk, qv.x, acc.x);
        acc.y = fmaf(wk, qv.y, acc.y);
        acc.z = fmaf(wk, qv.z, acc.z);
        acc.w = fmaf(wk, qv.w, acc.w);
      }
    }
  }
  *(float4*)(out + (size_t)row * CQ_ + lane * 4) = acc;
}

// ---------------------------------------------------------------------------
extern "C" void kernel_launch(void* const* d_in, const int* in_sizes, int n_in,
                              void* d_out, int out_size, void* d_ws, size_t ws_size,
                              hipStream_t stream) {
  const float* q  = (const float*)d_in[0];
  const float* ct = (const float*)d_in[1];
  const float* Wa = (const float*)d_in[2];
  const float* Wp = (const float*)d_in[3];
  const float* Vp = (const float*)d_in[4];
  float* out = (float*)d_out;

  // ws (floats): p[4096] | WpT[256*128]  -> 147 KB
  float* ws     = (float*)d_ws;
  float* p_ws   = ws;
  float* WpT_ws = ws + NB * S_LEN;

  k_prep <<<CC_, HPAD, 0, stream>>>(Wp, WpT_ws);
  k_align<<<(NB * S_LEN) / RB, 384, 0, stream>>>(ct, Wa, WpT_ws, Vp, p_ws, out);
  k_attn <<<(NB * S_LEN) / 4, 256, 0, stream>>>(q, p_ws, out, out);
}